// Round 3
// baseline (705.726 us; speedup 1.0000x reference)
//
#include <hip/hip_runtime.h>

typedef __bf16 bf16_t;
typedef __bf16 bf16x8 __attribute__((ext_vector_type(8)));
typedef float  f32x4  __attribute__((ext_vector_type(4)));

#define MFMA16(a, b, c) __builtin_amdgcn_mfma_f32_16x16x32_bf16((a), (b), (c), 0, 0, 0)
#define LOG2E 1.44269504f

// DPP rotate within 16-lane row (VALU-speed cross-lane, no LDS pipe).
// row_ror:N ctrl = 0x120 + N. Rotate-allreduce with N=8,4,2,1 covers all 16.
#define DPP_ROR(x, N) __int_as_float(__builtin_amdgcn_update_dpp( \
    0, __float_as_int(x), 0x120 + (N), 0xF, 0xF, true))

// 8-element loaders -> bf16x8 (fp32 source converts on the fly)
__device__ inline bf16x8 load8(const bf16_t* p) { return *(const bf16x8*)p; }
__device__ inline bf16x8 load8(const float* p) {
    f32x4 a = *(const f32x4*)p;
    f32x4 b = *(const f32x4*)(p + 4);
    bf16x8 r;
    r[0] = (bf16_t)a[0]; r[1] = (bf16_t)a[1]; r[2] = (bf16_t)a[2]; r[3] = (bf16_t)a[3];
    r[4] = (bf16_t)b[0]; r[5] = (bf16_t)b[1]; r[6] = (bf16_t)b[2]; r[7] = (bf16_t)b[3];
    return r;
}

// ---------------------------------------------------------------------------
// cvt_er: Er fp32 (1024x64) -> bf16 (1152x64), tail 128 rows zero-filled so
// the attention Er loads need no bounds checks.
// ---------------------------------------------------------------------------
__global__ void cvt_er(const float* __restrict__ Er, bf16_t* __restrict__ Erb)
{
    const int idx = blockIdx.x * 256 + threadIdx.x;   // grid 288 -> 73728
    Erb[idx] = (idx < 65536) ? (bf16_t)Er[idx] : (bf16_t)0.0f;
}

// ---------------------------------------------------------------------------
// gemm128: C[m,n] = X[m,:] . W[n,:] + bias[n]   (X @ W^T + b)
// 128x128 tile, BK=64, 4 waves in 2x2, each wave owns a 64x64 sub-tile as a
// 4x4 grid of 16x16 fragments.
// mode 0: (B,H,S,64) head-major; mode 1: flat [m*768+n];
// mode 2: (B,H,64,S) head-major TRANSPOSED (for V -> PV needs V^T).
// Fragment mapping (verified m89): C/D row = quad*4+r, col = l16.
// ---------------------------------------------------------------------------
template <typename XT, typename WT, typename OT>
__device__ __forceinline__ void
gemm128(const XT* __restrict__ X, const WT* __restrict__ W,
        const float* __restrict__ bias, OT* __restrict__ Out, int mode,
        int m0, int n0, bf16_t (*Al)[72], bf16_t (*Bl)[72])
{
    const int tid  = threadIdx.x;
    const int w    = tid >> 6;
    const int lane = tid & 63;
    const int quad = lane >> 4;
    const int l16  = lane & 15;
    const int wr   = (w >> 1) * 64;      // wave row offset in tile
    const int wc   = (w & 1) * 64;       // wave col offset in tile

    f32x4 acc[4][4];
#pragma unroll
    for (int mi = 0; mi < 4; ++mi)
#pragma unroll
        for (int ni = 0; ni < 4; ++ni)
#pragma unroll
            for (int r = 0; r < 4; ++r) acc[mi][ni][r] = 0.0f;

    const int srow = tid >> 3;          // 0..31
    const int scol = (tid & 7) * 8;     // 0..56

    for (int kc = 0; kc < 12; ++kc) {
        const int k0 = kc * 64;
        __syncthreads();
#pragma unroll
        for (int p = 0; p < 4; ++p) {
            const int row = p * 32 + srow;
            *(bf16x8*)&Al[row][scol] = load8(X + (size_t)(m0 + row) * 768 + k0 + scol);
            *(bf16x8*)&Bl[row][scol] = load8(W + (size_t)(n0 + row) * 768 + k0 + scol);
        }
        __syncthreads();
#pragma unroll
        for (int kk = 0; kk < 2; ++kk) {
            bf16x8 a[4], b[4];
#pragma unroll
            for (int mi = 0; mi < 4; ++mi)
                a[mi] = *(const bf16x8*)&Al[wr + mi * 16 + l16][kk * 32 + quad * 8];
#pragma unroll
            for (int ni = 0; ni < 4; ++ni)
                b[ni] = *(const bf16x8*)&Bl[wc + ni * 16 + l16][kk * 32 + quad * 8];
#pragma unroll
            for (int mi = 0; mi < 4; ++mi)
#pragma unroll
                for (int ni = 0; ni < 4; ++ni)
                    acc[mi][ni] = MFMA16(a[mi], b[ni], acc[mi][ni]);
        }
    }

#pragma unroll
    for (int ni = 0; ni < 4; ++ni) {
        const int n  = n0 + wc + ni * 16 + l16;
        const float bn = bias[n];
#pragma unroll
        for (int mi = 0; mi < 4; ++mi) {
#pragma unroll
            for (int r = 0; r < 4; ++r) {
                const int m = m0 + wr + mi * 16 + quad * 4 + r;
                const float v = acc[mi][ni][r] + bn;
                if (mode == 0) {
                    const int bb = m >> 10, ss = m & 1023, hh = n >> 6, dd = n & 63;
                    Out[(((size_t)(bb * 12 + hh)) * 1024 + ss) * 64 + dd] = (OT)v;
                } else if (mode == 2) {
                    const int bb = m >> 10, ss = m & 1023, hh = n >> 6, dd = n & 63;
                    Out[(((size_t)(bb * 12 + hh)) * 64 + dd) * 1024 + ss] = (OT)v;
                } else {
                    Out[(size_t)m * 768 + n] = (OT)v;
                }
            }
        }
    }
}

__global__ void __launch_bounds__(256)
qkv_proj(const float* __restrict__ Q, const float* __restrict__ K,
         const float* __restrict__ V,
         const float* __restrict__ Wq, const float* __restrict__ Wk,
         const float* __restrict__ Wv,
         const float* __restrict__ bq, const float* __restrict__ bk,
         const float* __restrict__ bv,
         bf16_t* __restrict__ qo, bf16_t* __restrict__ ko, bf16_t* __restrict__ vo)
{
    __shared__ bf16_t Al[128][72];
    __shared__ bf16_t Bl[128][72];
    const int z = blockIdx.z;
    const float* X  = (z == 0) ? Q  : (z == 1) ? K  : V;
    const float* W  = (z == 0) ? Wq : (z == 1) ? Wk : Wv;
    const float* bs = (z == 0) ? bq : (z == 1) ? bk : bv;
    bf16_t* Out     = (z == 0) ? qo : (z == 1) ? ko : vo;
    gemm128<float, float, bf16_t>(X, W, bs, Out, (z == 2) ? 2 : 0,
                                  blockIdx.x * 128, blockIdx.y * 128, Al, Bl);
}

__global__ void __launch_bounds__(256)
out_proj(const bf16_t* __restrict__ X, const float* __restrict__ W,
         const float* __restrict__ bias, float* __restrict__ Out)
{
    __shared__ bf16_t Al[128][72];
    __shared__ bf16_t Bl[128][72];
    gemm128<bf16_t, float, float>(X, W, bias, Out, 1,
                                  blockIdx.x * 128, blockIdx.y * 128, Al, Bl);
}

// ---------------------------------------------------------------------------
// attn_kernel: MFMA flash attention with Music-Transformer relative position.
// Block = (b, h, 64 q-rows). 4 waves x 16 q-rows.
// R3: ZERO LDS staging, ZERO barriers. K is (t,64)-row-major and V is
// pre-transposed (B,H,64,S), so both the QK and PV B-fragments are 16B
// contiguous GLOBAL loads (L2/L1-hot: K/V = 128KB/head, shared by the 4
// waves of a block). Er fragments also load from global (128KB, L2-hot).
// Waves are fully independent -> load latency hidden by TLP instead of
// landing on a barrier-locked critical path (m169 lesson: don't LDS-stage
// what the cache already holds). LDS = P round-trip only (9.2KB).
// Softmax reductions on the VALU DPP pipe. setprio(1) around MFMA clusters.
// ---------------------------------------------------------------------------
__global__ void __launch_bounds__(256, 4)
attn_kernel(const bf16_t* __restrict__ qb, const bf16_t* __restrict__ kb,
            const bf16_t* __restrict__ vt, const bf16_t* __restrict__ Erb,
            bf16_t* __restrict__ att)
{
    __shared__ bf16_t Pl[4][16][72];     // per-wave P round-trip (wave-private)

    const int tid  = threadIdx.x;
    const int bid  = blockIdx.x;
    const int qt   = 15 - (bid & 15);    // heavy q-tiles dispatched first
    const int bh   = bid >> 4;           // 0..95
    const int b    = bh / 12;
    const int h    = bh % 12;
    const int s0   = qt * 64;
    const int w    = tid >> 6;
    const int lane = tid & 63;
    const int quad = lane >> 4;
    const int l16  = lane & 15;
    const int s0w  = s0 + 16 * w;
    const int u0   = 48 - 16 * w;

    const bf16_t* qp = qb + (size_t)bh * 65536;
    const bf16_t* kp = kb + (size_t)bh * 65536;
    const bf16_t* vp = vt + (size_t)bh * 65536;   // (64 d) x (1024 t)

    // q fragments (A-layout: [m=l16][k=quad*8+j])
    bf16x8 aq[2];
#pragma unroll
    for (int kk = 0; kk < 2; ++kk)
        aq[kk] = load8(qp + (size_t)(s0w + l16) * 64 + kk * 32 + quad * 8);

    const int E00 = 960 - s0;

    float mrow[4], lrow[4];
    f32x4 o[4];
#pragma unroll
    for (int r = 0; r < 4; ++r) { mrow[r] = -1e30f; lrow[r] = 0.0f; }
#pragma unroll
    for (int nt = 0; nt < 4; ++nt)
#pragma unroll
        for (int r = 0; r < 4; ++r) o[nt][r] = 0.0f;

    const int nT = qt + 1;
    for (int tt = 0; tt < nT; ++tt) {
        const int t0 = tt * 64;
        const int E0 = E00 + t0;
        const int ebase = E0 + u0 + l16;

        // --- K fragments straight from global (B-frag: n=t row, k=d) ---
        bf16x8 bk0[4], bk1[4];
#pragma unroll
        for (int nt = 0; nt < 4; ++nt) {
            if (t0 + nt * 16 <= s0w + 15) {         // wave-uniform mask skip
                const bf16_t* kr = kp + (size_t)(t0 + nt * 16 + l16) * 64 + quad * 8;
                bk0[nt] = load8(kr);
                bk1[nt] = load8(kr + 32);
            }
        }
        // --- Er fragments (kk=0 half) ---
        bf16x8 be0[5];
#pragma unroll
        for (int gt = 0; gt < 5; ++gt)
            be0[gt] = load8(Erb + (size_t)(ebase + gt * 16) * 64 + quad * 8);

        f32x4 sacc[4], gacc[5];
#pragma unroll
        for (int nt = 0; nt < 4; ++nt)
#pragma unroll
            for (int r = 0; r < 4; ++r) sacc[nt][r] = 0.0f;
#pragma unroll
        for (int gt = 0; gt < 5; ++gt)
#pragma unroll
            for (int r = 0; r < 4; ++r) gacc[gt][r] = 0.0f;

        // --- QK^T ---
        __builtin_amdgcn_s_setprio(1);
#pragma unroll
        for (int nt = 0; nt < 4; ++nt)
            if (t0 + nt * 16 <= s0w + 15)
                sacc[nt] = MFMA16(aq[0], bk0[nt], sacc[nt]);
#pragma unroll
        for (int nt = 0; nt < 4; ++nt)
            if (t0 + nt * 16 <= s0w + 15)
                sacc[nt] = MFMA16(aq[1], bk1[nt], sacc[nt]);
        __builtin_amdgcn_s_setprio(0);

        // --- Er kk=1 half flies while kk=0 G-MFMAs run ---
        bf16x8 be1[5];
#pragma unroll
        for (int gt = 0; gt < 5; ++gt)
            be1[gt] = load8(Erb + (size_t)(ebase + gt * 16) * 64 + 32 + quad * 8);
        __builtin_amdgcn_s_setprio(1);
#pragma unroll
        for (int gt = 0; gt < 5; ++gt)
            gacc[gt] = MFMA16(aq[0], be0[gt], gacc[gt]);
#pragma unroll
        for (int gt = 0; gt < 5; ++gt)
            gacc[gt] = MFMA16(aq[1], be1[gt], gacc[gt]);
        __builtin_amdgcn_s_setprio(0);

        // --- V fragments issued now; latency hidden under skew+softmax ---
        bf16x8 bv0[4], bv1[4];
#pragma unroll
        for (int nt = 0; nt < 4; ++nt) {
            const bf16_t* vr = vp + (size_t)(nt * 16 + l16) * 1024 + t0 + quad * 8;
            bv0[nt] = load8(vr);
            bv1[nt] = load8(vr + 32);
        }

        // --- skew via quad-local rotation + logits + causal mask ---
        // Srel row i=quad*4+r needs G[i][15-i+j]: same quad, same reg r,
        // lane (l16 + 15-i)&15; tile nt if l16<=i else nt+1.
#pragma unroll
        for (int r = 0; r < 4; ++r) {
            const int i   = quad * 4 + r;
            const int cc  = 15 - i + l16;              // 0..30
            const int src = (lane & 48) | (cc & 15);
            const bool lo = (cc < 16);
            float rot[5];
#pragma unroll
            for (int gt = 0; gt < 5; ++gt) rot[gt] = __shfl(gacc[gt][r], src);
#pragma unroll
            for (int nt = 0; nt < 4; ++nt) {
                const float g = lo ? rot[nt] : rot[nt + 1];
                float sv = (sacc[nt][r] + g) * 0.125f;
                if (t0 + nt * 16 + l16 > s0w + i) sv = -1e9f;
                sacc[nt][r] = sv;
            }
        }

        // --- online softmax: DPP rotate-allreduce over the 16-lane row ---
#pragma unroll
        for (int r = 0; r < 4; ++r) {
            float vm = fmaxf(fmaxf(sacc[0][r], sacc[1][r]), fmaxf(sacc[2][r], sacc[3][r]));
            vm = fmaxf(vm, DPP_ROR(vm, 8));
            vm = fmaxf(vm, DPP_ROR(vm, 4));
            vm = fmaxf(vm, DPP_ROR(vm, 2));
            vm = fmaxf(vm, DPP_ROR(vm, 1));
            const float mnew  = fmaxf(mrow[r], vm);
            const float alpha = __builtin_exp2f((mrow[r] - mnew) * LOG2E);
            mrow[r] = mnew;
            float rs = 0.0f;
#pragma unroll
            for (int nt = 0; nt < 4; ++nt) {
                const float p_ = __builtin_exp2f((sacc[nt][r] - mnew) * LOG2E);
                sacc[nt][r] = p_;
                rs += p_;
            }
            rs += DPP_ROR(rs, 8);
            rs += DPP_ROR(rs, 4);
            rs += DPP_ROR(rs, 2);
            rs += DPP_ROR(rs, 1);
            lrow[r] = lrow[r] * alpha + rs;
            o[0][r] *= alpha; o[1][r] *= alpha;
            o[2][r] *= alpha; o[3][r] *= alpha;
        }

        // --- P to wave-private LDS (C/D -> A transpose), then PV ---
#pragma unroll
        for (int nt = 0; nt < 4; ++nt)
#pragma unroll
            for (int r = 0; r < 4; ++r)
                Pl[w][quad * 4 + r][nt * 16 + l16] = (bf16_t)sacc[nt][r];

        bf16x8 ap0 = *(const bf16x8*)&Pl[w][l16][quad * 8];
        bf16x8 ap1 = *(const bf16x8*)&Pl[w][l16][32 + quad * 8];
        __builtin_amdgcn_s_setprio(1);
#pragma unroll
        for (int nt = 0; nt < 4; ++nt) {
            o[nt] = MFMA16(ap0, bv0[nt], o[nt]);
            o[nt] = MFMA16(ap1, bv1[nt], o[nt]);
        }
        __builtin_amdgcn_s_setprio(0);
    }

    // --- epilogue: att[b, s, h*64+d] = o / l ---
#pragma unroll
    for (int nt = 0; nt < 4; ++nt) {
#pragma unroll
        for (int r = 0; r < 4; ++r) {
            const int s_idx = s0w + quad * 4 + r;
            const int d     = nt * 16 + l16;
            att[((size_t)b * 1024 + s_idx) * 768 + h * 64 + d] = (bf16_t)(o[nt][r] / lrow[r]);
        }
    }
}

// ---------------------------------------------------------------------------
extern "C" void kernel_launch(void* const* d_in, const int* in_sizes, int n_in,
                              void* d_out, int out_size, void* d_ws, size_t ws_size,
                              hipStream_t stream)
{
    const float* Q  = (const float*)d_in[0];
    const float* K  = (const float*)d_in[1];
    const float* V  = (const float*)d_in[2];
    // d_in[3] = causal mask — semantics reproduced in-kernel
    const float* Wq = (const float*)d_in[4];
    const float* bq = (const float*)d_in[5];
    const float* Wk = (const float*)d_in[6];
    const float* bk = (const float*)d_in[7];
    const float* Wv = (const float*)d_in[8];
    const float* bv = (const float*)d_in[9];
    const float* Wo = (const float*)d_in[10];
    const float* bo = (const float*)d_in[11];
    const float* Er = (const float*)d_in[12];
    float* out      = (float*)d_out;     // fp32 output (reference dtype)

    const size_t per = (size_t)8 * 12 * 1024 * 64;   // 6.29M elems
    // d_out (25.2MB fp32) front: qbuf (bf16, 12.6MB) + Erb (144KB) — both dead
    // before the fp32 out_proj epilogue overwrites d_out.
    bf16_t* qbuf  = (bf16_t*)d_out;
    bf16_t* Erb   = qbuf + per;          // 1152 x 64 bf16, zero tail
    bf16_t* kbuf  = (bf16_t*)d_ws;
    bf16_t* vtbuf = kbuf + per;          // (B,H,64,S) V^T
    bf16_t* abuf  = vtbuf + per;         // (B,S,768) attention out, bf16

    cvt_er<<<dim3(288), dim3(256), 0, stream>>>(Er, Erb);
    qkv_proj<<<dim3(64, 6, 3), dim3(256), 0, stream>>>(Q, K, V, Wq, Wk, Wv,
                                                       bq, bk, bv, qbuf, kbuf, vtbuf);
    attn_kernel<<<dim3(1536), dim3(256), 0, stream>>>(qbuf, kbuf, vtbuf, Erb, abuf);
    out_proj<<<dim3(64, 6), dim3(256), 0, stream>>>(abuf, Wo, bo, out);
}

// Round 4
// 347.998 us; speedup vs baseline: 2.0280x; 2.0280x over previous
//
#include <hip/hip_runtime.h>

typedef __bf16 bf16_t;
typedef __bf16 bf16x8 __attribute__((ext_vector_type(8)));
typedef float  f32x4  __attribute__((ext_vector_type(4)));

#define MFMA16(a, b, c) __builtin_amdgcn_mfma_f32_16x16x32_bf16((a), (b), (c), 0, 0, 0)
#define LOG2E 1.44269504f

// DPP rotate within 16-lane row (VALU-speed cross-lane, no LDS pipe).
// row_ror:N ctrl = 0x120 + N. Rotate-allreduce with N=8,4,2,1 covers all 16.
#define DPP_ROR(x, N) __int_as_float(__builtin_amdgcn_update_dpp( \
    0, __float_as_int(x), 0x120 + (N), 0xF, 0xF, true))

// 8-element loaders -> bf16x8 (fp32 source converts on the fly)
__device__ inline bf16x8 load8(const bf16_t* p) { return *(const bf16x8*)p; }
__device__ inline bf16x8 load8(const float* p) {
    f32x4 a = *(const f32x4*)p;
    f32x4 b = *(const f32x4*)(p + 4);
    bf16x8 r;
    r[0] = (bf16_t)a[0]; r[1] = (bf16_t)a[1]; r[2] = (bf16_t)a[2]; r[3] = (bf16_t)a[3];
    r[4] = (bf16_t)b[0]; r[5] = (bf16_t)b[1]; r[6] = (bf16_t)b[2]; r[7] = (bf16_t)b[3];
    return r;
}

// ---------------------------------------------------------------------------
// cvt_er: Er fp32 (1024x64) -> bf16 (1152x64), tail 128 rows zero-filled so
// the attention staging needs no bounds checks.
// ---------------------------------------------------------------------------
__global__ void cvt_er(const float* __restrict__ Er, bf16_t* __restrict__ Erb)
{
    const int idx = blockIdx.x * 256 + threadIdx.x;   // grid 288 -> 73728
    Erb[idx] = (idx < 65536) ? (bf16_t)Er[idx] : (bf16_t)0.0f;
}

// ---------------------------------------------------------------------------
// gemm128: C[m,n] = X[m,:] . W[n,:] + bias[n]   (X @ W^T + b)
// 128x128 tile, BK=64, 4 waves in 2x2, each wave owns a 64x64 sub-tile as a
// 4x4 grid of 16x16 fragments.
// mode 0: (B,H,S,64) head-major; mode 1: flat [m*768+n];
// mode 2: (B,H,64,S) head-major TRANSPOSED (for V -> PV needs V^T).
// Fragment mapping (verified m89): C/D row = quad*4+r, col = l16.
// ---------------------------------------------------------------------------
template <typename XT, typename WT, typename OT>
__device__ __forceinline__ void
gemm128(const XT* __restrict__ X, const WT* __restrict__ W,
        const float* __restrict__ bias, OT* __restrict__ Out, int mode,
        int m0, int n0, bf16_t (*Al)[72], bf16_t (*Bl)[72])
{
    const int tid  = threadIdx.x;
    const int w    = tid >> 6;
    const int lane = tid & 63;
    const int quad = lane >> 4;
    const int l16  = lane & 15;
    const int wr   = (w >> 1) * 64;      // wave row offset in tile
    const int wc   = (w & 1) * 64;       // wave col offset in tile

    f32x4 acc[4][4];
#pragma unroll
    for (int mi = 0; mi < 4; ++mi)
#pragma unroll
        for (int ni = 0; ni < 4; ++ni)
#pragma unroll
            for (int r = 0; r < 4; ++r) acc[mi][ni][r] = 0.0f;

    const int srow = tid >> 3;          // 0..31
    const int scol = (tid & 7) * 8;     // 0..56

    for (int kc = 0; kc < 12; ++kc) {
        const int k0 = kc * 64;
        __syncthreads();
#pragma unroll
        for (int p = 0; p < 4; ++p) {
            const int row = p * 32 + srow;
            *(bf16x8*)&Al[row][scol] = load8(X + (size_t)(m0 + row) * 768 + k0 + scol);
            *(bf16x8*)&Bl[row][scol] = load8(W + (size_t)(n0 + row) * 768 + k0 + scol);
        }
        __syncthreads();
#pragma unroll
        for (int kk = 0; kk < 2; ++kk) {
            bf16x8 a[4], b[4];
#pragma unroll
            for (int mi = 0; mi < 4; ++mi)
                a[mi] = *(const bf16x8*)&Al[wr + mi * 16 + l16][kk * 32 + quad * 8];
#pragma unroll
            for (int ni = 0; ni < 4; ++ni)
                b[ni] = *(const bf16x8*)&Bl[wc + ni * 16 + l16][kk * 32 + quad * 8];
#pragma unroll
            for (int mi = 0; mi < 4; ++mi)
#pragma unroll
                for (int ni = 0; ni < 4; ++ni)
                    acc[mi][ni] = MFMA16(a[mi], b[ni], acc[mi][ni]);
        }
    }

#pragma unroll
    for (int ni = 0; ni < 4; ++ni) {
        const int n  = n0 + wc + ni * 16 + l16;
        const float bn = bias[n];
#pragma unroll
        for (int mi = 0; mi < 4; ++mi) {
#pragma unroll
            for (int r = 0; r < 4; ++r) {
                const int m = m0 + wr + mi * 16 + quad * 4 + r;
                const float v = acc[mi][ni][r] + bn;
                if (mode == 0) {
                    const int bb = m >> 10, ss = m & 1023, hh = n >> 6, dd = n & 63;
                    Out[(((size_t)(bb * 12 + hh)) * 1024 + ss) * 64 + dd] = (OT)v;
                } else if (mode == 2) {
                    const int bb = m >> 10, ss = m & 1023, hh = n >> 6, dd = n & 63;
                    Out[(((size_t)(bb * 12 + hh)) * 64 + dd) * 1024 + ss] = (OT)v;
                } else {
                    Out[(size_t)m * 768 + n] = (OT)v;
                }
            }
        }
    }
}

__global__ void __launch_bounds__(256)
qkv_proj(const float* __restrict__ Q, const float* __restrict__ K,
         const float* __restrict__ V,
         const float* __restrict__ Wq, const float* __restrict__ Wk,
         const float* __restrict__ Wv,
         const float* __restrict__ bq, const float* __restrict__ bk,
         const float* __restrict__ bv,
         bf16_t* __restrict__ qo, bf16_t* __restrict__ ko, bf16_t* __restrict__ vo)
{
    __shared__ bf16_t Al[128][72];
    __shared__ bf16_t Bl[128][72];
    const int z = blockIdx.z;
    const float* X  = (z == 0) ? Q  : (z == 1) ? K  : V;
    const float* W  = (z == 0) ? Wq : (z == 1) ? Wk : Wv;
    const float* bs = (z == 0) ? bq : (z == 1) ? bk : bv;
    bf16_t* Out     = (z == 0) ? qo : (z == 1) ? ko : vo;
    gemm128<float, float, bf16_t>(X, W, bs, Out, (z == 2) ? 2 : 0,
                                  blockIdx.x * 128, blockIdx.y * 128, Al, Bl);
}

__global__ void __launch_bounds__(256)
out_proj(const bf16_t* __restrict__ X, const float* __restrict__ W,
         const float* __restrict__ bias, float* __restrict__ Out)
{
    __shared__ bf16_t Al[128][72];
    __shared__ bf16_t Bl[128][72];
    gemm128<bf16_t, float, float>(X, W, bias, Out, 1,
                                  blockIdx.x * 128, blockIdx.y * 128, Al, Bl);
}

// ---------------------------------------------------------------------------
// attn_kernel: MFMA flash attention with Music-Transformer relative position.
// R4: LOAD-BALANCED block pairing. Block = (bh, pr) processes q-tile qt=pr
// then qt=15-pr -> every block runs exactly 17 K-tile iterations. Grid=768
// = 256 CUs x 3 blocks (46KB LDS => 3 blocks/CU), so ALL blocks are
// co-resident from t=0 and finish together (fixes the avg-occupancy-12%
// load-imbalance tail seen in R1-R3 counters).
// Per-tile structure = verified R1: Erl LDS ring, K/V LDS staging with
// register prefetch, quad-local skew rotation. Softmax reductions on the
// VALU DPP pipe (row_ror) + s_setprio around MFMA clusters (R2-verified).
// ---------------------------------------------------------------------------
__global__ void __launch_bounds__(256)
attn_kernel(const bf16_t* __restrict__ qb, const bf16_t* __restrict__ kb,
            const bf16_t* __restrict__ vt, const bf16_t* __restrict__ Erb,
            bf16_t* __restrict__ att)
{
    __shared__ bf16_t Kl[64][72];        // K tile, row t_local
    __shared__ bf16_t Vtl[64][72];       // V^T tile: [d][t_local] (direct stage)
    __shared__ bf16_t Erl[128][72];      // Er ring: phys row = e & 127
    __shared__ bf16_t Pl[4][16][72];     // per-wave P round-trip (wave-private)

    const int tid  = threadIdx.x;
    const int bid  = blockIdx.x;         // 0..767
    const int bh   = bid >> 3;           // 0..95
    const int pr   = bid & 7;            // pair index
    const int b    = bh / 12;
    const int h    = bh % 12;
    const int w    = tid >> 6;
    const int lane = tid & 63;
    const int quad = lane >> 4;
    const int l16  = lane & 15;
    const int u0   = 48 - 16 * w;
    const int srow = tid >> 3;          // 0..31
    const int scol = (tid & 7) * 8;     // 0..56

    const bf16_t* qp = qb + (size_t)bh * 65536;
    const bf16_t* kp = kb + (size_t)bh * 65536;
    const bf16_t* vp = vt + (size_t)bh * 65536;   // (64 d) x (1024 t)

#pragma unroll 1
    for (int phase = 0; phase < 2; ++phase) {
        const int qt  = phase ? (15 - pr) : pr;   // nT sums to 17 per block
        const int s0  = qt * 64;
        const int s0w = s0 + 16 * w;
        const int E00 = 960 - s0;

        // q fragments (A-layout: [m=l16][k=quad*8+j])
        bf16x8 aq[2];
#pragma unroll
        for (int kk = 0; kk < 2; ++kk)
            aq[kk] = load8(qp + (size_t)(s0w + l16) * 64 + kk * 32 + quad * 8);

        // protect LDS reuse across phases (prev phase readers done)
        __syncthreads();

        // --- initial stage: tile 0 + full 128-row Er window ---
#pragma unroll
        for (int p = 0; p < 2; ++p) {
            *(bf16x8*)&Kl[p * 32 + srow][scol]  = load8(kp + (size_t)(p * 32 + srow) * 64 + scol);
            *(bf16x8*)&Vtl[p * 32 + srow][scol] = load8(vp + (size_t)(p * 32 + srow) * 1024 + scol);
        }
#pragma unroll
        for (int p = 0; p < 4; ++p) {
            const int e = E00 + p * 32 + srow;
            *(bf16x8*)&Erl[e & 127][scol] = load8(Erb + (size_t)e * 64 + scol);
        }
        __syncthreads();

        float mrow[4], lrow[4];
        f32x4 o[4];
#pragma unroll
        for (int r = 0; r < 4; ++r) { mrow[r] = -1e30f; lrow[r] = 0.0f; }
#pragma unroll
        for (int nt = 0; nt < 4; ++nt)
#pragma unroll
            for (int r = 0; r < 4; ++r) o[nt][r] = 0.0f;

        const int nT = qt + 1;
        for (int tt = 0; tt < nT; ++tt) {
            const int t0 = tt * 64;
            const int E0 = E00 + t0;
            const bool more = (tt + 1 < nT);

            // --- prefetch next tile into registers (in flight during compute) ---
            bf16x8 kpre[2], vpre[2], epre[2];
            if (more) {
                const int t0n = t0 + 64;
#pragma unroll
                for (int p = 0; p < 2; ++p) {
                    kpre[p] = load8(kp + (size_t)(t0n + p * 32 + srow) * 64 + scol);
                    vpre[p] = load8(vp + (size_t)(p * 32 + srow) * 1024 + t0n + scol);
                    const int e = E0 + 128 + p * 32 + srow;     // new 64 rows of window
                    epre[p] = load8(Erb + (size_t)e * 64 + scol);
                }
            }

            // --- QK^T and G strip via MFMA ---
            f32x4 sacc[4], gacc[5];
#pragma unroll
            for (int nt = 0; nt < 4; ++nt)
#pragma unroll
                for (int r = 0; r < 4; ++r) sacc[nt][r] = 0.0f;
#pragma unroll
            for (int gt = 0; gt < 5; ++gt)
#pragma unroll
                for (int r = 0; r < 4; ++r) gacc[gt][r] = 0.0f;

            __builtin_amdgcn_s_setprio(1);
#pragma unroll
            for (int kk = 0; kk < 2; ++kk) {
#pragma unroll
                for (int nt = 0; nt < 4; ++nt) {
                    if (t0 + nt * 16 <= s0w + 15) {   // wave-uniform: skip fully-masked tiles
                        bf16x8 bk_ = *(const bf16x8*)&Kl[nt * 16 + l16][kk * 32 + quad * 8];
                        sacc[nt] = MFMA16(aq[kk], bk_, sacc[nt]);
                    }
                }
#pragma unroll
                for (int gt = 0; gt < 5; ++gt) {
                    const int er = (E0 + u0 + gt * 16 + l16) & 127;
                    bf16x8 be = *(const bf16x8*)&Erl[er][kk * 32 + quad * 8];
                    gacc[gt] = MFMA16(aq[kk], be, gacc[gt]);
                }
            }
            __builtin_amdgcn_s_setprio(0);

            // --- skew via quad-local rotation + logits + causal mask ---
            // Srel row i=quad*4+r needs G[i][15-i+j]: same quad, same reg r,
            // lane (l16 + 15-i)&15; tile nt if l16<=i else nt+1.
#pragma unroll
            for (int r = 0; r < 4; ++r) {
                const int i   = quad * 4 + r;
                const int cc  = 15 - i + l16;              // 0..30
                const int src = (lane & 48) | (cc & 15);
                const bool lo = (cc < 16);
                float rot[5];
#pragma unroll
                for (int gt = 0; gt < 5; ++gt) rot[gt] = __shfl(gacc[gt][r], src);
#pragma unroll
                for (int nt = 0; nt < 4; ++nt) {
                    const float g = lo ? rot[nt] : rot[nt + 1];
                    float sv = (sacc[nt][r] + g) * 0.125f;
                    if (t0 + nt * 16 + l16 > s0w + i) sv = -1e9f;
                    sacc[nt][r] = sv;
                }
            }

            // --- online softmax: DPP rotate-allreduce over the 16-lane row ---
#pragma unroll
            for (int r = 0; r < 4; ++r) {
                float vm = fmaxf(fmaxf(sacc[0][r], sacc[1][r]), fmaxf(sacc[2][r], sacc[3][r]));
                vm = fmaxf(vm, DPP_ROR(vm, 8));
                vm = fmaxf(vm, DPP_ROR(vm, 4));
                vm = fmaxf(vm, DPP_ROR(vm, 2));
                vm = fmaxf(vm, DPP_ROR(vm, 1));
                const float mnew  = fmaxf(mrow[r], vm);
                const float alpha = __builtin_exp2f((mrow[r] - mnew) * LOG2E);
                mrow[r] = mnew;
                float rs = 0.0f;
#pragma unroll
                for (int nt = 0; nt < 4; ++nt) {
                    const float p_ = __builtin_exp2f((sacc[nt][r] - mnew) * LOG2E);
                    sacc[nt][r] = p_;
                    rs += p_;
                }
                rs += DPP_ROR(rs, 8);
                rs += DPP_ROR(rs, 4);
                rs += DPP_ROR(rs, 2);
                rs += DPP_ROR(rs, 1);
                lrow[r] = lrow[r] * alpha + rs;
                o[0][r] *= alpha; o[1][r] *= alpha;
                o[2][r] *= alpha; o[3][r] *= alpha;
            }

            // --- P to wave-private LDS (C/D -> A transpose), then PV ---
#pragma unroll
            for (int nt = 0; nt < 4; ++nt)
#pragma unroll
                for (int r = 0; r < 4; ++r)
                    Pl[w][quad * 4 + r][nt * 16 + l16] = (bf16_t)sacc[nt][r];

            __builtin_amdgcn_s_setprio(1);
#pragma unroll
            for (int kk = 0; kk < 2; ++kk) {
                bf16x8 ap = *(const bf16x8*)&Pl[w][l16][kk * 32 + quad * 8];
#pragma unroll
                for (int nt = 0; nt < 4; ++nt) {
                    bf16x8 bv_ = *(const bf16x8*)&Vtl[nt * 16 + l16][kk * 32 + quad * 8];
                    o[nt] = MFMA16(ap, bv_, o[nt]);
                }
            }
            __builtin_amdgcn_s_setprio(0);

            // --- commit prefetched tile to LDS ---
            if (more) {
                __syncthreads();
#pragma unroll
                for (int p = 0; p < 2; ++p) {
                    *(bf16x8*)&Kl[p * 32 + srow][scol]  = kpre[p];
                    *(bf16x8*)&Vtl[p * 32 + srow][scol] = vpre[p];
                    const int e = E0 + p * 32 + srow;   // (E0+128+ro)&127 == (E0+ro)&127
                    *(bf16x8*)&Erl[e & 127][scol] = epre[p];
                }
                __syncthreads();
            }
        }

        // --- epilogue: att[b, s, h*64+d] = o / l ---
#pragma unroll
        for (int nt = 0; nt < 4; ++nt) {
#pragma unroll
            for (int r = 0; r < 4; ++r) {
                const int s_idx = s0w + quad * 4 + r;
                const int d     = nt * 16 + l16;
                att[((size_t)b * 1024 + s_idx) * 768 + h * 64 + d] = (bf16_t)(o[nt][r] / lrow[r]);
            }
        }
    }
}

// ---------------------------------------------------------------------------
extern "C" void kernel_launch(void* const* d_in, const int* in_sizes, int n_in,
                              void* d_out, int out_size, void* d_ws, size_t ws_size,
                              hipStream_t stream)
{
    const float* Q  = (const float*)d_in[0];
    const float* K  = (const float*)d_in[1];
    const float* V  = (const float*)d_in[2];
    // d_in[3] = causal mask — semantics reproduced in-kernel
    const float* Wq = (const float*)d_in[4];
    const float* bq = (const float*)d_in[5];
    const float* Wk = (const float*)d_in[6];
    const float* bk = (const float*)d_in[7];
    const float* Wv = (const float*)d_in[8];
    const float* bv = (const float*)d_in[9];
    const float* Wo = (const float*)d_in[10];
    const float* bo = (const float*)d_in[11];
    const float* Er = (const float*)d_in[12];
    float* out      = (float*)d_out;     // fp32 output (reference dtype)

    const size_t per = (size_t)8 * 12 * 1024 * 64;   // 6.29M elems
    // d_out (25.2MB fp32) front: qbuf (bf16, 12.6MB) + Erb (144KB) — both dead
    // before the fp32 out_proj epilogue overwrites d_out.
    bf16_t* qbuf  = (bf16_t*)d_out;
    bf16_t* Erb   = qbuf + per;          // 1152 x 64 bf16, zero tail
    bf16_t* kbuf  = (bf16_t*)d_ws;
    bf16_t* vtbuf = kbuf + per;          // (B,H,64,S) V^T
    bf16_t* abuf  = vtbuf + per;         // (B,S,768) attention out, bf16

    cvt_er<<<dim3(288), dim3(256), 0, stream>>>(Er, Erb);
    qkv_proj<<<dim3(64, 6, 3), dim3(256), 0, stream>>>(Q, K, V, Wq, Wk, Wv,
                                                       bq, bk, bv, qbuf, kbuf, vtbuf);
    attn_kernel<<<dim3(768), dim3(256), 0, stream>>>(qbuf, kbuf, vtbuf, Erb, abuf);
    out_proj<<<dim3(64, 6), dim3(256), 0, stream>>>(abuf, Wo, bo, out);
}

// Round 5
// 308.877 us; speedup vs baseline: 2.2848x; 1.1267x over previous
//
#include <hip/hip_runtime.h>

typedef __bf16 bf16_t;
typedef __bf16 bf16x8 __attribute__((ext_vector_type(8)));
typedef float  f32x4  __attribute__((ext_vector_type(4)));

#define MFMA16(a, b, c) __builtin_amdgcn_mfma_f32_16x16x32_bf16((a), (b), (c), 0, 0, 0)
#define LOG2E 1.44269504f

// DPP rotate within 16-lane row (VALU-speed cross-lane, no LDS pipe).
#define DPP_ROR(x, N) __int_as_float(__builtin_amdgcn_update_dpp( \
    0, __float_as_int(x), 0x120 + (N), 0xF, 0xF, true))

// 8-element loaders -> bf16x8 (fp32 source converts on the fly)
__device__ inline bf16x8 load8(const bf16_t* p) { return *(const bf16x8*)p; }
__device__ inline bf16x8 load8(const float* p) {
    f32x4 a = *(const f32x4*)p;
    f32x4 b = *(const f32x4*)(p + 4);
    bf16x8 r;
    r[0] = (bf16_t)a[0]; r[1] = (bf16_t)a[1]; r[2] = (bf16_t)a[2]; r[3] = (bf16_t)a[3];
    r[4] = (bf16_t)b[0]; r[5] = (bf16_t)b[1]; r[6] = (bf16_t)b[2]; r[7] = (bf16_t)b[3];
    return r;
}

// ---------------------------------------------------------------------------
// cvt_all: one pass converting Q,K,V (8x1024x768), Wq,Wk,Wv,Wo (768x768) and
// Er (1024x64 -> 1152x64 zero-tail) from fp32 to bf16. vec8 per thread.
// Segment boundaries in vec8 units.
// ---------------------------------------------------------------------------
__global__ void __launch_bounds__(256)
cvt_all(const float* __restrict__ Q, const float* __restrict__ K,
        const float* __restrict__ V, const float* __restrict__ Wq,
        const float* __restrict__ Wk, const float* __restrict__ Wv,
        const float* __restrict__ Wo, const float* __restrict__ Er,
        bf16_t* __restrict__ qxb, bf16_t* __restrict__ kxb,
        bf16_t* __restrict__ vxb, bf16_t* __restrict__ wqb,
        bf16_t* __restrict__ wkb, bf16_t* __restrict__ wvb,
        bf16_t* __restrict__ wob, bf16_t* __restrict__ Erb)
{
    const int idx = blockIdx.x * 256 + threadIdx.x;   // 0 .. 2663423
    const float* src;  bf16_t* dst;  int off;
    if      (idx <  786432) { src = Q;  dst = qxb; off = idx; }
    else if (idx < 1572864) { src = K;  dst = kxb; off = idx -  786432; }
    else if (idx < 2359296) { src = V;  dst = vxb; off = idx - 1572864; }
    else if (idx < 2433024) { src = Wq; dst = wqb; off = idx - 2359296; }
    else if (idx < 2506752) { src = Wk; dst = wkb; off = idx - 2433024; }
    else if (idx < 2580480) { src = Wv; dst = wvb; off = idx - 2506752; }
    else if (idx < 2654208) { src = Wo; dst = wob; off = idx - 2580480; }
    else {                                            // Er with zero tail
        off = idx - 2654208;                          // 0..9215 (src cap 8192)
        bf16x8 r;
        if (off < 8192) r = load8(Er + (size_t)off * 8);
        else { for (int j = 0; j < 8; ++j) r[j] = (bf16_t)0.0f; }
        *(bf16x8*)(Erb + (size_t)off * 8) = r;
        return;
    }
    *(bf16x8*)(dst + (size_t)off * 8) = load8(src + (size_t)off * 8);
}

// ---------------------------------------------------------------------------
// gemm_bt: C[m,n] = X[m,:] . W[n,:] + bias[n]   (X @ W^T + b), bf16 inputs.
// m97-pattern: 128x128 tile, BK=64, global_load_lds width-16 direct staging.
// LDS layout: 16 groups of 8 rows; group stride 528 elems (1056 B = 1024 B
// data + 32 B pad) -> gload writes stay contiguous per call, and the ds_read
// 16-lane column read splits into two 8-way bank groups (8 banks apart)
// instead of one 16-way conflict.
// mode 0: (B,H,S,64) head-major; mode 1: flat [m*768+n];
// mode 2: (B,H,64,S) head-major TRANSPOSED (for V -> PV needs V^T).
// Fragment mapping (verified m89): C/D row = quad*4+r, col = l16.
// ---------------------------------------------------------------------------
template <typename OT>
__device__ __forceinline__ void
gemm_bt(const bf16_t* __restrict__ X, const bf16_t* __restrict__ W,
        const float* __restrict__ bias, OT* __restrict__ Out, int mode,
        int m0, int n0, bf16_t* Al, bf16_t* Bl)
{
    const int tid  = threadIdx.x;
    const int w    = tid >> 6;
    const int lane = tid & 63;
    const int quad = lane >> 4;
    const int l16  = lane & 15;
    const int wr   = (w >> 1) * 64;      // wave row offset in tile
    const int wc   = (w & 1) * 64;       // wave col offset in tile
    const int l8r  = lane >> 3;          // 0..7 (row within 8-row group)
    const int l8c  = lane & 7;           // 0..7 (8-elem col chunk)

    f32x4 acc[4][4];
#pragma unroll
    for (int mi = 0; mi < 4; ++mi)
#pragma unroll
        for (int ni = 0; ni < 4; ++ni)
#pragma unroll
            for (int r = 0; r < 4; ++r) acc[mi][ni][r] = 0.0f;

    // per-lane global source for the wave's 32 rows (4 groups of 8)
    const bf16_t* gA = X + (size_t)(m0 + w * 32 + l8r) * 768 + l8c * 8;
    const bf16_t* gB = W + (size_t)(n0 + w * 32 + l8r) * 768 + l8c * 8;

    for (int kc = 0; kc < 12; ++kc) {
        const int k0 = kc * 64;
        __syncthreads();
#pragma unroll
        for (int p = 0; p < 4; ++p) {
            __builtin_amdgcn_global_load_lds(
                (__attribute__((address_space(1))) const void*)(gA + (size_t)p * 8 * 768 + k0),
                (__attribute__((address_space(3))) void*)(Al + (w * 4 + p) * 528), 16, 0, 0);
            __builtin_amdgcn_global_load_lds(
                (__attribute__((address_space(1))) const void*)(gB + (size_t)p * 8 * 768 + k0),
                (__attribute__((address_space(3))) void*)(Bl + (w * 4 + p) * 528), 16, 0, 0);
        }
        __syncthreads();
#pragma unroll
        for (int kk = 0; kk < 2; ++kk) {
            bf16x8 a[4], b[4];
#pragma unroll
            for (int mi = 0; mi < 4; ++mi) {
                const int row = wr + mi * 16 + l16;
                a[mi] = *(const bf16x8*)&Al[(row >> 3) * 528 + (row & 7) * 64 + kk * 32 + quad * 8];
            }
#pragma unroll
            for (int ni = 0; ni < 4; ++ni) {
                const int row = wc + ni * 16 + l16;
                b[ni] = *(const bf16x8*)&Bl[(row >> 3) * 528 + (row & 7) * 64 + kk * 32 + quad * 8];
            }
#pragma unroll
            for (int mi = 0; mi < 4; ++mi)
#pragma unroll
                for (int ni = 0; ni < 4; ++ni)
                    acc[mi][ni] = MFMA16(a[mi], b[ni], acc[mi][ni]);
        }
    }

#pragma unroll
    for (int ni = 0; ni < 4; ++ni) {
        const int n  = n0 + wc + ni * 16 + l16;
        const float bn = bias[n];
#pragma unroll
        for (int mi = 0; mi < 4; ++mi) {
#pragma unroll
            for (int r = 0; r < 4; ++r) {
                const int m = m0 + wr + mi * 16 + quad * 4 + r;
                const float v = acc[mi][ni][r] + bn;
                if (mode == 0) {
                    const int bb = m >> 10, ss = m & 1023, hh = n >> 6, dd = n & 63;
                    Out[(((size_t)(bb * 12 + hh)) * 1024 + ss) * 64 + dd] = (OT)v;
                } else if (mode == 2) {
                    const int bb = m >> 10, ss = m & 1023, hh = n >> 6, dd = n & 63;
                    Out[(((size_t)(bb * 12 + hh)) * 64 + dd) * 1024 + ss] = (OT)v;
                } else {
                    Out[(size_t)m * 768 + n] = (OT)v;
                }
            }
        }
    }
}

__global__ void __launch_bounds__(256)
qkv_proj(const bf16_t* __restrict__ Qx, const bf16_t* __restrict__ Kx,
         const bf16_t* __restrict__ Vx,
         const bf16_t* __restrict__ Wq, const bf16_t* __restrict__ Wk,
         const bf16_t* __restrict__ Wv,
         const float* __restrict__ bq, const float* __restrict__ bk,
         const float* __restrict__ bv,
         bf16_t* __restrict__ qo, bf16_t* __restrict__ ko, bf16_t* __restrict__ vo)
{
    __shared__ bf16_t Al[16 * 528];
    __shared__ bf16_t Bl[16 * 528];
    const int z = blockIdx.z;
    const bf16_t* X  = (z == 0) ? Qx : (z == 1) ? Kx : Vx;
    const bf16_t* W  = (z == 0) ? Wq : (z == 1) ? Wk : Wv;
    const float* bs  = (z == 0) ? bq : (z == 1) ? bk : bv;
    bf16_t* Out      = (z == 0) ? qo : (z == 1) ? ko : vo;
    gemm_bt<bf16_t>(X, W, bs, Out, (z == 2) ? 2 : 0,
                    blockIdx.x * 128, blockIdx.y * 128, Al, Bl);
}

__global__ void __launch_bounds__(256)
out_proj(const bf16_t* __restrict__ X, const bf16_t* __restrict__ W,
         const float* __restrict__ bias, float* __restrict__ Out)
{
    __shared__ bf16_t Al[16 * 528];
    __shared__ bf16_t Bl[16 * 528];
    gemm_bt<float>(X, W, bias, Out, 1, blockIdx.x * 128, blockIdx.y * 128, Al, Bl);
}

// ---------------------------------------------------------------------------
// attn_kernel: MFMA flash attention with Music-Transformer relative position.
// R4 (verified): LOAD-BALANCED block pairing. Block = (bh, pr) processes
// q-tile qt=pr then qt=15-pr -> every block runs exactly 17 K-tile
// iterations. Grid=768 = 256 CUs x 3 blocks, all co-resident from t=0.
// Per-tile structure: Erl LDS ring, K/V LDS staging with register prefetch,
// quad-local skew rotation, DPP softmax, s_setprio around MFMA clusters.
// ---------------------------------------------------------------------------
__global__ void __launch_bounds__(256)
attn_kernel(const bf16_t* __restrict__ qb, const bf16_t* __restrict__ kb,
            const bf16_t* __restrict__ vt, const bf16_t* __restrict__ Erb,
            bf16_t* __restrict__ att)
{
    __shared__ bf16_t Kl[64][72];        // K tile, row t_local
    __shared__ bf16_t Vtl[64][72];       // V^T tile: [d][t_local] (direct stage)
    __shared__ bf16_t Erl[128][72];      // Er ring: phys row = e & 127
    __shared__ bf16_t Pl[4][16][72];     // per-wave P round-trip (wave-private)

    const int tid  = threadIdx.x;
    const int bid  = blockIdx.x;         // 0..767
    const int bh   = bid >> 3;           // 0..95
    const int pr   = bid & 7;            // pair index
    const int b    = bh / 12;
    const int h    = bh % 12;
    const int w    = tid >> 6;
    const int lane = tid & 63;
    const int quad = lane >> 4;
    const int l16  = lane & 15;
    const int u0   = 48 - 16 * w;
    const int srow = tid >> 3;          // 0..31
    const int scol = (tid & 7) * 8;     // 0..56

    const bf16_t* qp = qb + (size_t)bh * 65536;
    const bf16_t* kp = kb + (size_t)bh * 65536;
    const bf16_t* vp = vt + (size_t)bh * 65536;   // (64 d) x (1024 t)

#pragma unroll 1
    for (int phase = 0; phase < 2; ++phase) {
        const int qt  = phase ? (15 - pr) : pr;   // nT sums to 17 per block
        const int s0  = qt * 64;
        const int s0w = s0 + 16 * w;
        const int E00 = 960 - s0;

        // q fragments (A-layout: [m=l16][k=quad*8+j])
        bf16x8 aq[2];
#pragma unroll
        for (int kk = 0; kk < 2; ++kk)
            aq[kk] = load8(qp + (size_t)(s0w + l16) * 64 + kk * 32 + quad * 8);

        // protect LDS reuse across phases (prev phase readers done)
        __syncthreads();

        // --- initial stage: tile 0 + full 128-row Er window ---
#pragma unroll
        for (int p = 0; p < 2; ++p) {
            *(bf16x8*)&Kl[p * 32 + srow][scol]  = load8(kp + (size_t)(p * 32 + srow) * 64 + scol);
            *(bf16x8*)&Vtl[p * 32 + srow][scol] = load8(vp + (size_t)(p * 32 + srow) * 1024 + scol);
        }
#pragma unroll
        for (int p = 0; p < 4; ++p) {
            const int e = E00 + p * 32 + srow;
            *(bf16x8*)&Erl[e & 127][scol] = load8(Erb + (size_t)e * 64 + scol);
        }
        __syncthreads();

        float mrow[4], lrow[4];
        f32x4 o[4];
#pragma unroll
        for (int r = 0; r < 4; ++r) { mrow[r] = -1e30f; lrow[r] = 0.0f; }
#pragma unroll
        for (int nt = 0; nt < 4; ++nt)
#pragma unroll
            for (int r = 0; r < 4; ++r) o[nt][r] = 0.0f;

        const int nT = qt + 1;
        for (int tt = 0; tt < nT; ++tt) {
            const int t0 = tt * 64;
            const int E0 = E00 + t0;
            const bool more = (tt + 1 < nT);

            // --- prefetch next tile into registers (in flight during compute) ---
            bf16x8 kpre[2], vpre[2], epre[2];
            if (more) {
                const int t0n = t0 + 64;
#pragma unroll
                for (int p = 0; p < 2; ++p) {
                    kpre[p] = load8(kp + (size_t)(t0n + p * 32 + srow) * 64 + scol);
                    vpre[p] = load8(vp + (size_t)(p * 32 + srow) * 1024 + t0n + scol);
                    const int e = E0 + 128 + p * 32 + srow;     // new 64 rows of window
                    epre[p] = load8(Erb + (size_t)e * 64 + scol);
                }
            }

            // --- QK^T and G strip via MFMA ---
            f32x4 sacc[4], gacc[5];
#pragma unroll
            for (int nt = 0; nt < 4; ++nt)
#pragma unroll
                for (int r = 0; r < 4; ++r) sacc[nt][r] = 0.0f;
#pragma unroll
            for (int gt = 0; gt < 5; ++gt)
#pragma unroll
                for (int r = 0; r < 4; ++r) gacc[gt][r] = 0.0f;

            __builtin_amdgcn_s_setprio(1);
#pragma unroll
            for (int kk = 0; kk < 2; ++kk) {
#pragma unroll
                for (int nt = 0; nt < 4; ++nt) {
                    if (t0 + nt * 16 <= s0w + 15) {   // wave-uniform: skip fully-masked tiles
                        bf16x8 bk_ = *(const bf16x8*)&Kl[nt * 16 + l16][kk * 32 + quad * 8];
                        sacc[nt] = MFMA16(aq[kk], bk_, sacc[nt]);
                    }
                }
#pragma unroll
                for (int gt = 0; gt < 5; ++gt) {
                    const int er = (E0 + u0 + gt * 16 + l16) & 127;
                    bf16x8 be = *(const bf16x8*)&Erl[er][kk * 32 + quad * 8];
                    gacc[gt] = MFMA16(aq[kk], be, gacc[gt]);
                }
            }
            __builtin_amdgcn_s_setprio(0);

            // --- skew via quad-local rotation + logits + causal mask ---
            // Srel row i=quad*4+r needs G[i][15-i+j]: same quad, same reg r,
            // lane (l16 + 15-i)&15; tile nt if l16<=i else nt+1.
#pragma unroll
            for (int r = 0; r < 4; ++r) {
                const int i   = quad * 4 + r;
                const int cc  = 15 - i + l16;              // 0..30
                const int src = (lane & 48) | (cc & 15);
                const bool lo = (cc < 16);
                float rot[5];
#pragma unroll
                for (int gt = 0; gt < 5; ++gt) rot[gt] = __shfl(gacc[gt][r], src);
#pragma unroll
                for (int nt = 0; nt < 4; ++nt) {
                    const float g = lo ? rot[nt] : rot[nt + 1];
                    float sv = (sacc[nt][r] + g) * 0.125f;
                    if (t0 + nt * 16 + l16 > s0w + i) sv = -1e9f;
                    sacc[nt][r] = sv;
                }
            }

            // --- online softmax: DPP rotate-allreduce over the 16-lane row ---
#pragma unroll
            for (int r = 0; r < 4; ++r) {
                float vm = fmaxf(fmaxf(sacc[0][r], sacc[1][r]), fmaxf(sacc[2][r], sacc[3][r]));
                vm = fmaxf(vm, DPP_ROR(vm, 8));
                vm = fmaxf(vm, DPP_ROR(vm, 4));
                vm = fmaxf(vm, DPP_ROR(vm, 2));
                vm = fmaxf(vm, DPP_ROR(vm, 1));
                const float mnew  = fmaxf(mrow[r], vm);
                const float alpha = __builtin_exp2f((mrow[r] - mnew) * LOG2E);
                mrow[r] = mnew;
                float rs = 0.0f;
#pragma unroll
                for (int nt = 0; nt < 4; ++nt) {
                    const float p_ = __builtin_exp2f((sacc[nt][r] - mnew) * LOG2E);
                    sacc[nt][r] = p_;
                    rs += p_;
                }
                rs += DPP_ROR(rs, 8);
                rs += DPP_ROR(rs, 4);
                rs += DPP_ROR(rs, 2);
                rs += DPP_ROR(rs, 1);
                lrow[r] = lrow[r] * alpha + rs;
                o[0][r] *= alpha; o[1][r] *= alpha;
                o[2][r] *= alpha; o[3][r] *= alpha;
            }

            // --- P to wave-private LDS (C/D -> A transpose), then PV ---
#pragma unroll
            for (int nt = 0; nt < 4; ++nt)
#pragma unroll
                for (int r = 0; r < 4; ++r)
                    Pl[w][quad * 4 + r][nt * 16 + l16] = (bf16_t)sacc[nt][r];

            __builtin_amdgcn_s_setprio(1);
#pragma unroll
            for (int kk = 0; kk < 2; ++kk) {
                bf16x8 ap = *(const bf16x8*)&Pl[w][l16][kk * 32 + quad * 8];
#pragma unroll
                for (int nt = 0; nt < 4; ++nt) {
                    bf16x8 bv_ = *(const bf16x8*)&Vtl[nt * 16 + l16][kk * 32 + quad * 8];
                    o[nt] = MFMA16(ap, bv_, o[nt]);
                }
            }
            __builtin_amdgcn_s_setprio(0);

            // --- commit prefetched tile to LDS ---
            if (more) {
                __syncthreads();
#pragma unroll
                for (int p = 0; p < 2; ++p) {
                    *(bf16x8*)&Kl[p * 32 + srow][scol]  = kpre[p];
                    *(bf16x8*)&Vtl[p * 32 + srow][scol] = vpre[p];
                    const int e = E0 + p * 32 + srow;   // (E0+128+ro)&127 == (E0+ro)&127
                    *(bf16x8*)&Erl[e & 127][scol] = epre[p];
                }
                __syncthreads();
            }
        }

        // --- epilogue: att[b, s, h*64+d] = o / l ---
#pragma unroll
        for (int nt = 0; nt < 4; ++nt) {
#pragma unroll
            for (int r = 0; r < 4; ++r) {
                const int s_idx = s0w + quad * 4 + r;
                const int d     = nt * 16 + l16;
                att[((size_t)b * 1024 + s_idx) * 768 + h * 64 + d] = (bf16_t)(o[nt][r] / lrow[r]);
            }
        }
    }
}

// ---------------------------------------------------------------------------
extern "C" void kernel_launch(void* const* d_in, const int* in_sizes, int n_in,
                              void* d_out, int out_size, void* d_ws, size_t ws_size,
                              hipStream_t stream)
{
    const float* Q  = (const float*)d_in[0];
    const float* K  = (const float*)d_in[1];
    const float* V  = (const float*)d_in[2];
    // d_in[3] = causal mask — semantics reproduced in-kernel
    const float* Wq = (const float*)d_in[4];
    const float* bq = (const float*)d_in[5];
    const float* Wk = (const float*)d_in[6];
    const float* bk = (const float*)d_in[7];
    const float* Wv = (const float*)d_in[8];
    const float* bv = (const float*)d_in[9];
    const float* Wo = (const float*)d_in[10];
    const float* bo = (const float*)d_in[11];
    const float* Er = (const float*)d_in[12];
    float* out      = (float*)d_out;     // fp32 output (reference dtype)

    const size_t per = (size_t)8 * 12 * 1024 * 64;   // 6.29M elems
    const size_t wsz = (size_t)768 * 768;            // 589824 elems

    // d_out (25.17MB) hosts qxb + qbuf (2 x 12.58MB, exact fit). Both dead
    // before out_proj's fp32 epilogue overwrites d_out.
    bf16_t* qxb   = (bf16_t*)d_out;      // bf16 Q input (dead after qkv_proj)
    bf16_t* qbuf  = qxb + per;           // projected q (dead after attn)

    // workspace: ~53 MB
    bf16_t* kbuf  = (bf16_t*)d_ws;       // projected k
    bf16_t* vtbuf = kbuf + per;          // projected V^T (B,H,64,S)
    bf16_t* kxb   = vtbuf + per;         // bf16 K input; REUSED as abuf after qkv
    bf16_t* vxb   = kxb + per;           // bf16 V input
    bf16_t* wqb   = vxb + per;
    bf16_t* wkb   = wqb + wsz;
    bf16_t* wvb   = wkb + wsz;
    bf16_t* wob   = wvb + wsz;
    bf16_t* Erb   = wob + wsz;           // 1152 x 64 bf16, zero tail
    bf16_t* abuf  = kxb;                 // alias: kxb dead once qkv_proj done

    cvt_all<<<dim3(10404), dim3(256), 0, stream>>>(Q, K, V, Wq, Wk, Wv, Wo, Er,
                                                   qxb, kxb, vxb, wqb, wkb, wvb,
                                                   wob, Erb);
    qkv_proj<<<dim3(64, 6, 3), dim3(256), 0, stream>>>(qxb, kxb, vxb, wqb, wkb, wvb,
                                                       bq, bk, bv, qbuf, kbuf, vtbuf);
    attn_kernel<<<dim3(768), dim3(256), 0, stream>>>(qbuf, kbuf, vtbuf, Erb, abuf);
    out_proj<<<dim3(64, 6), dim3(256), 0, stream>>>(abuf, wob, bo, out);
}